// Round 5
// baseline (24593.625 us; speedup 1.0000x reference)
//
#include <hip/hip_runtime.h>

#define LL 12
#define BB 8
#define HH 12
#define EE 768
#define DD 64
#define SS 1024
#define VV 50257
#define E3 2304
#define E4 3072
#define KCH 64
#define NCH 9        // attention chunks per (b,h), 64 rows each (covers kv<=576)
#define CROWS 64
#define NCOMP 864
#define NCOPY 160
#define GRID_ (NCOMP + NCOPY)
#define N4HALF 18874368ull   // float4 per KV buffer

typedef float f4_ __attribute__((ext_vector_type(4)));

__device__ __forceinline__ float gelu_tanh(float v) {
    float c = 0.7978845608028654f * (v + 0.044715f * v * v * v);
    return 0.5f * v * (1.0f + tanhf(c));
}

// device-scope generation barrier over NCOMP blocks
__device__ __forceinline__ void grid_barrier(unsigned* bar) {
    __syncthreads();
    if (threadIdx.x == 0) {
        __threadfence();  // release: make this block's stores device-visible
        unsigned g = __hip_atomic_load(bar + 1, __ATOMIC_RELAXED, __HIP_MEMORY_SCOPE_AGENT);
        unsigned a = __hip_atomic_fetch_add(bar, 1u, __ATOMIC_ACQ_REL, __HIP_MEMORY_SCOPE_AGENT);
        if (a == NCOMP - 1) {
            __hip_atomic_store(bar, 0u, __ATOMIC_RELAXED, __HIP_MEMORY_SCOPE_AGENT);
            __hip_atomic_store(bar + 1, g + 1u, __ATOMIC_RELEASE, __HIP_MEMORY_SCOPE_AGENT);
        } else {
            while (__hip_atomic_load(bar + 1, __ATOMIC_ACQUIRE, __HIP_MEMORY_SCOPE_AGENT) == g)
                __builtin_amdgcn_s_sleep(2);
        }
        __threadfence();  // acquire: invalidate stale cached lines
    }
    __syncthreads();
}

// per-row LN stats over (h1+h2): 8 rows x 32 lanes
__device__ __forceinline__ void ln_stats(const float* __restrict__ h1, const float* __restrict__ h2,
                                         float* mean, float* rstd) {
    int t = threadIdx.x, r = t >> 5, l = t & 31;
    float s = 0.f, ss = 0.f;
#pragma unroll
    for (int i = 0; i < 24; i++) {
        int e = l + i * 32;
        float v = h1[r * EE + e] + h2[r * EE + e];
        s += v; ss += v * v;
    }
#pragma unroll
    for (int m = 16; m >= 1; m >>= 1) { s += __shfl_xor(s, m); ss += __shfl_xor(ss, m); }
    if (l == 0) {
        float mu = s * (1.f / EE);
        mean[r] = mu;
        rstd[r] = rsqrtf(ss * (1.f / EE) - mu * mu + 1e-5f);
    }
}

// xl[8][KCH] x W[KCH x 64cols] -> atomicAdd out[8][64cols]
__device__ __forceinline__ void gemm_tile(const float* __restrict__ xl, const float* __restrict__ W,
                                          float* __restrict__ out, int e0, int c0, int C) {
    int t = threadIdx.x;
    int c = c0 + (t & 63);
    int r2 = (t >> 6) * 2;
    const float* Wp = W + (size_t)e0 * C + c;
    float a0 = 0.f, a1 = 0.f;
#pragma unroll
    for (int e = 0; e < KCH; e++) {
        float w = Wp[(size_t)e * C];
        a0 += xl[r2 * KCH + e] * w;
        a1 += xl[(r2 + 1) * KCH + e] * w;
    }
    atomicAdd(&out[(size_t)r2 * C + c], a0);
    atomicAdd(&out[(size_t)(r2 + 1) * C + c], a1);
}

__global__ __launch_bounds__(256, 4) void k_all(
    const int* __restrict__ ids, const int* __restrict__ posp,
    const float* __restrict__ past_k, const float* __restrict__ past_v,
    const float* __restrict__ wte, const float* __restrict__ wpe,
    const float* __restrict__ ln1g, const float* __restrict__ ln1b,
    const float* __restrict__ aw, const float* __restrict__ ab,
    const float* __restrict__ pw, const float* __restrict__ pb,
    const float* __restrict__ ln2g, const float* __restrict__ ln2b,
    const float* __restrict__ fw, const float* __restrict__ fb,
    const float* __restrict__ fpw, const float* __restrict__ fpb,
    const float* __restrict__ lnfg, const float* __restrict__ lnfb,
    float* __restrict__ logits, float* __restrict__ okeys, float* __restrict__ ovals,
    unsigned* __restrict__ bar,
    float* __restrict__ hB, float* __restrict__ hA, float* __restrict__ tmlp,
    float* __restrict__ tproj, float* __restrict__ qkv, float* __restrict__ fcbuf,
    float* __restrict__ pm, float* __restrict__ psum, float* __restrict__ po) {

    int blk = blockIdx.x, t = threadIdx.x;
    int pos = *posp, kv = pos + 1;

    // ---------------- dedicated copy blocks: stream whole KV copy, no barriers --
    if (blk >= NCOMP) {
        const f4_* kq = (const f4_*)past_k;
        const f4_* vq = (const f4_*)past_v;
        f4_* ko = (f4_*)okeys;
        f4_* vo = (f4_*)ovals;
        const size_t tot = 2 * N4HALF;
        for (size_t i = (size_t)(blk - NCOMP) * 256 + t; i < tot; i += (size_t)NCOPY * 256) {
            int row = (int)((i >> 4) & (SS - 1));
            if (row == pos) continue;
            if (i < N4HALF) {
                f4_ v = __builtin_nontemporal_load(kq + i);
                __builtin_nontemporal_store(v, ko + i);
            } else {
                size_t j = i - N4HALF;
                f4_ v = __builtin_nontemporal_load(vq + j);
                __builtin_nontemporal_store(v, vo + j);
            }
        }
        return;
    }

    // ---------------- compute blocks ----------------
    __shared__ union {
        struct { float xl[8 * KCH]; } g;
        struct { float xl[8 * EE]; } lg;
        struct { float qs[DD]; float s[CROWS]; float red[256]; float bc[2]; } a;
    } sm;
    __shared__ float s_mean[8], s_rstd[8];

    int vb = blk;

    // prologue: embed(24) | tmlp=0(24) | qkv=ab0(72)
    if (vb < 24) {
        int i = vb * 256 + t, b = i / EE, e = i % EE;
        hB[i] = wte[(size_t)ids[b] * EE + e] + wpe[(size_t)pos * EE + e];
    } else if (vb < 48) {
        tmlp[(vb - 24) * 256 + t] = 0.f;
    } else if (vb < 120) {
        int i = (vb - 48) * 256 + t;
        qkv[i] = ab[i % E3];
    }
    grid_barrier(bar);

    for (int l = 0; l < LL; l++) {
        const float* aw_l = aw + (size_t)l * EE * E3;
        const float* pw_l = pw + (size_t)l * EE * EE;
        const float* fw_l = fw + (size_t)l * EE * E4;
        const float* fpw_l = fpw + (size_t)l * E4 * EE;
        const size_t co = (size_t)l * BB * HH * SS * DD;

        // ---- P0: x=LN1(hB+tmlp); qkv += x@aw | hA=hB+tmlp | tproj=pb | fcbuf=fb
        if (vb < 432) {
            ln_stats(hB, tmlp, s_mean, s_rstd);
            __syncthreads();
            int chunk = vb / 36, colblk = vb % 36;
            int e0 = chunk * KCH, c0 = colblk * 64;
            for (int i = t; i < 8 * KCH; i += 256) {
                int b = i >> 6, ll2 = i & 63, e = e0 + ll2;
                sm.g.xl[i] = (hB[b * EE + e] + tmlp[b * EE + e] - s_mean[b]) * s_rstd[b]
                             * ln1g[l * EE + e] + ln1b[l * EE + e];
            }
            __syncthreads();
            gemm_tile(sm.g.xl, aw_l, qkv, e0, c0, E3);
        } else if (vb < 456) {
            int i = (vb - 432) * 256 + t;
            hA[i] = hB[i] + tmlp[i];
        } else if (vb < 480) {
            int i = (vb - 456) * 256 + t;
            tproj[i] = pb[l * EE + i % EE];
        } else if (vb < 576) {
            int i = (vb - 480) * 256 + t;
            fcbuf[i] = fb[(size_t)l * E4 + i % E4];
        }
        grid_barrier(bar);

        // ---- P1: attention partials (+ write new K/V row at pos)
        if (vb < BB * HH * NCH) {
            int ch = vb % NCH, bh = vb / NCH;
            int b = bh / HH, hh = bh % HH;
            int j0 = ch * CROWS;
            int idx = bh * NCH + ch;
            if (j0 >= kv) {
                if (t == 0) psum[idx] = 0.f;
            } else {
                const size_t off = co + (size_t)bh * SS * DD;
                const float* Kc = past_k + off;
                const float* Vc = past_v + off;
                const float* qn = qkv + (size_t)b * E3 + hh * DD;
                const float* kn = qn + EE;
                const float* vn = qn + 2 * EE;

                if (t < DD) sm.a.qs[t] = qn[t];
                __syncthreads();

                int row = t >> 2, q = t & 3;
                int j = j0 + row;
                float sj = 0.f;
                if (j < kv) {
                    const float4* s4 = (const float4*)(((j == pos) ? kn : (Kc + (size_t)j * DD)) + q * 16);
#pragma unroll
                    for (int i = 0; i < 4; i++) {
                        float4 k4 = s4[i];
                        int e = q * 16 + 4 * i;
                        sj += k4.x * sm.a.qs[e] + k4.y * sm.a.qs[e + 1] + k4.z * sm.a.qs[e + 2] + k4.w * sm.a.qs[e + 3];
                    }
                }
                sj += __shfl_xor(sj, 1);
                sj += __shfl_xor(sj, 2);
                if (j == pos) {
                    float4* dst = (float4*)(okeys + off + (size_t)pos * DD + q * 16);
                    const float4* sn = (const float4*)(kn + q * 16);
#pragma unroll
                    for (int i = 0; i < 4; i++) dst[i] = sn[i];
                }
                if (q == 0) sm.a.s[row] = (j < kv) ? sj * 0.125f : -INFINITY;
                __syncthreads();

                if (t < 64) {
                    float v = sm.a.s[t];
#pragma unroll
                    for (int m = 1; m <= 32; m <<= 1) v = fmaxf(v, __shfl_xor(v, m));
                    if (t == 0) sm.a.bc[0] = v;
                }
                __syncthreads();
                float m = sm.a.bc[0];
                if (t < 64) sm.a.s[t] = __expf(sm.a.s[t] - m);
                __syncthreads();
                if (t < 64) {
                    float p = sm.a.s[t];
#pragma unroll
                    for (int mm = 1; mm <= 32; mm <<= 1) p += __shfl_xor(p, mm);
                    if (t == 0) sm.a.bc[1] = p;
                }

                int d = t & 63, grp = t >> 6;
                float od = 0.f;
                for (int jj = j0 + grp; jj < j0 + CROWS; jj += 4) {
                    if (jj == pos) {
                        float vv = vn[d];
                        ovals[off + (size_t)pos * DD + d] = vv;
                        od += sm.a.s[jj - j0] * vv;
                    } else if (jj < kv) {
                        od += sm.a.s[jj - j0] * Vc[(size_t)jj * DD + d];
                    }
                }
                __syncthreads();
                sm.a.red[t] = od;
                __syncthreads();
                if (t < 64) {
                    float tt = sm.a.red[t] + sm.a.red[64 + t] + sm.a.red[128 + t] + sm.a.red[192 + t];
                    po[(size_t)idx * 64 + t] = tt;
                }
                if (t == 0) { pm[idx] = m; psum[idx] = sm.a.bc[1]; }
            }
        }
        grid_barrier(bar);

        // ---- P2: o=combine(partials); tproj += o@pw | tmlp=fpb
        if (vb < 144) {
            int chunk = vb / 12, colblk = vb % 12;
            int e0 = chunk * KCH, c0 = colblk * 64;
            for (int i = t; i < 8 * KCH; i += 256) {
                int b = i >> 6, ll2 = i & 63;
                int e = e0 + ll2;
                int hh = e >> 6, d = e & 63;
                int bh = b * HH + hh;
                float M = -INFINITY;
#pragma unroll
                for (int ch = 0; ch < NCH; ch++) {
                    int idx = bh * NCH + ch;
                    if (psum[idx] > 0.f) M = fmaxf(M, pm[idx]);
                }
                float den = 0.f, acc = 0.f;
#pragma unroll
                for (int ch = 0; ch < NCH; ch++) {
                    int idx = bh * NCH + ch;
                    float ps = psum[idx];
                    if (ps > 0.f) {
                        float f = __expf(pm[idx] - M);
                        den += ps * f;
                        acc += po[(size_t)idx * 64 + d] * f;
                    }
                }
                sm.g.xl[i] = acc / den;
            }
            __syncthreads();
            gemm_tile(sm.g.xl, pw_l, tproj, e0, c0, EE);
        } else if (vb < 168) {
            int i = (vb - 144) * 256 + t;
            tmlp[i] = fpb[l * EE + i % EE];
        }
        grid_barrier(bar);

        // ---- P3: x2=LN2(hA+tproj); fcbuf += x2@fw | hB=hA+tproj
        if (vb < 576) {
            ln_stats(hA, tproj, s_mean, s_rstd);
            __syncthreads();
            int chunk = vb / 48, colblk = vb % 48;
            int e0 = chunk * KCH, c0 = colblk * 64;
            for (int i = t; i < 8 * KCH; i += 256) {
                int b = i >> 6, ll2 = i & 63, e = e0 + ll2;
                sm.g.xl[i] = (hA[b * EE + e] + tproj[b * EE + e] - s_mean[b]) * s_rstd[b]
                             * ln2g[l * EE + e] + ln2b[l * EE + e];
            }
            __syncthreads();
            gemm_tile(sm.g.xl, fw_l, fcbuf, e0, c0, E4);
        } else if (vb < 600) {
            int i = (vb - 576) * 256 + t;
            hB[i] = hA[i] + tproj[i];
        }
        grid_barrier(bar);

        // ---- P4: tmlp += gelu(fcbuf)@fpw | qkv=ab[l+1]
        if (vb < 576) {
            int chunk = vb / 12, colblk = vb % 12;
            int e0 = chunk * KCH, c0 = colblk * 64;
            for (int i = t; i < 8 * KCH; i += 256) {
                int b = i >> 6, ll2 = i & 63;
                sm.g.xl[i] = gelu_tanh(fcbuf[(size_t)b * E4 + e0 + ll2]);
            }
            __syncthreads();
            gemm_tile(sm.g.xl, fpw_l, tmlp, e0, c0, EE);
        } else if (l < LL - 1 && vb < 648) {
            int i = (vb - 576) * 256 + t;
            qkv[i] = ab[(size_t)(l + 1) * E3 + i % E3];
        }
        grid_barrier(bar);
    }

    // ---- logits = lnf(hB+tmlp) @ wte^T
    if (vb < 786) {
        ln_stats(hB, tmlp, s_mean, s_rstd);
        __syncthreads();
        for (int i = t; i < 8 * EE; i += 256) {
            int b = i / EE, e = i % EE;
            sm.lg.xl[i] = (hB[i] + tmlp[i] - s_mean[b]) * s_rstd[b] * lnfg[e] + lnfb[e];
        }
        __syncthreads();
        int v = vb * 64 + (t >> 2);
        if (v < VV) {
            int el = t & 3;
            const float4* w = (const float4*)(wte + (size_t)v * EE);
            float acc[8] = {0, 0, 0, 0, 0, 0, 0, 0};
            for (int i = el; i < 192; i += 4) {
                float4 w4 = w[i];
#pragma unroll
                for (int b = 0; b < 8; b++) {
                    float4 xx = ((const float4*)(sm.lg.xl + b * EE))[i];
                    acc[b] += w4.x * xx.x + w4.y * xx.y + w4.z * xx.z + w4.w * xx.w;
                }
            }
#pragma unroll
            for (int b = 0; b < 8; b++) {
                acc[b] += __shfl_xor(acc[b], 1);
                acc[b] += __shfl_xor(acc[b], 2);
            }
            if (el == 0) {
#pragma unroll
                for (int b = 0; b < 8; b++) logits[(size_t)b * VV + v] = acc[b];
            }
        }
    }
}

extern "C" void kernel_launch(void* const* d_in, const int* in_sizes, int n_in,
                              void* d_out, int out_size, void* d_ws, size_t ws_size,
                              hipStream_t stream) {
    const int* ids = (const int*)d_in[0];
    const int* posp = (const int*)d_in[1];
    const float* past_k = (const float*)d_in[2];
    const float* past_v = (const float*)d_in[3];
    const float* wte = (const float*)d_in[4];
    const float* wpe = (const float*)d_in[5];
    const float* ln1g = (const float*)d_in[6];
    const float* ln1b = (const float*)d_in[7];
    const float* aw = (const float*)d_in[8];
    const float* ab = (const float*)d_in[9];
    const float* pw = (const float*)d_in[10];
    const float* pb = (const float*)d_in[11];
    const float* ln2g = (const float*)d_in[12];
    const float* ln2b = (const float*)d_in[13];
    const float* fw = (const float*)d_in[14];
    const float* fb = (const float*)d_in[15];
    const float* fpw = (const float*)d_in[16];
    const float* fpb = (const float*)d_in[17];
    const float* lnfg = (const float*)d_in[18];
    const float* lnfb = (const float*)d_in[19];

    float* logits = (float*)d_out;
    float* okeys = logits + (size_t)BB * VV;
    float* ovals = okeys + (size_t)LL * BB * HH * SS * DD;

    unsigned* bar = (unsigned*)d_ws;
    float* base = (float*)((char*)d_ws + 64);
    float* hB = base;
    float* hA = hB + BB * EE;
    float* tmlp = hA + BB * EE;
    float* tproj = tmlp + BB * EE;
    float* qkv = tproj + BB * EE;
    float* fcbuf = qkv + BB * E3;
    float* pm = fcbuf + BB * E4;
    float* psum = pm + BB * HH * NCH;
    float* po = psum + BB * HH * NCH;

    hipMemsetAsync(bar, 0, 64, stream);
    k_all<<<GRID_, 256, 0, stream>>>(
        ids, posp, past_k, past_v, wte, wpe, ln1g, ln1b, aw, ab, pw, pb,
        ln2g, ln2b, fw, fb, fpw, fpb, lnfg, lnfb,
        logits, okeys, ovals, bar,
        hB, hA, tmlp, tproj, qkv, fcbuf, pm, psum, po);
}

// Round 6
// 3331.948 us; speedup vs baseline: 7.3812x; 7.3812x over previous
//
#include <hip/hip_runtime.h>

#define LL 12
#define BB 8
#define HH 12
#define EE 768
#define DD 64
#define SS 1024
#define VV 50257
#define E3 2304
#define E4 3072
#define KCH 64
#define NCH 9        // attention chunks per (b,h), 64 rows each (covers kv<=576)
#define CROWS 64
#define NCOMP 864
#define NCOPY 160
#define GRID_ (NCOMP + NCOPY)
#define N4HALF 18874368ull   // float4 per KV buffer

typedef float f4_ __attribute__((ext_vector_type(4)));

__device__ __forceinline__ float gelu_tanh(float v) {
    float c = 0.7978845608028654f * (v + 0.044715f * v * v * v);
    return 0.5f * v * (1.0f + tanhf(c));
}

// ---- grid barrier over NCOMP blocks -------------------------------------
// Hierarchical monotonic counters: 8 sub-counters (128B apart) -> master -> flag.
// Relaxed polls (no per-poll cache maintenance); one release/acquire fence pair
// per block per barrier. Counters never reset (no reset/arrival race).
__device__ __forceinline__ void grid_barrier(unsigned* bar) {
    // bar layout (unsigned words): sub[k] at k*32, master at 512, flag at 544
    __syncthreads();   // drains vmcnt -> this block's stores are in its L2
    if (threadIdx.x == 0) {
        __builtin_amdgcn_fence(__ATOMIC_RELEASE, "agent");   // wbl2: publish our stores
        unsigned k = blockIdx.x & 7;
        unsigned a = __hip_atomic_fetch_add(bar + k * 32, 1u, __ATOMIC_RELAXED, __HIP_MEMORY_SCOPE_AGENT);
        unsigned gen = a / (NCOMP / 8);
        if (a % (NCOMP / 8) == (NCOMP / 8) - 1) {
            unsigned m = __hip_atomic_fetch_add(bar + 512, 1u, __ATOMIC_RELAXED, __HIP_MEMORY_SCOPE_AGENT);
            if ((m & 7u) == 7u)
                __hip_atomic_store(bar + 544, gen + 1u, __ATOMIC_RELAXED, __HIP_MEMORY_SCOPE_AGENT);
            else
                while (__hip_atomic_load(bar + 544, __ATOMIC_RELAXED, __HIP_MEMORY_SCOPE_AGENT) <= gen)
                    __builtin_amdgcn_s_sleep(16);
        } else {
            while (__hip_atomic_load(bar + 544, __ATOMIC_RELAXED, __HIP_MEMORY_SCOPE_AGENT) <= gen)
                __builtin_amdgcn_s_sleep(16);
        }
        __builtin_amdgcn_fence(__ATOMIC_ACQUIRE, "agent");   // inv: see others' stores
    }
    __syncthreads();
}

// per-row LN stats over (h1+h2): 8 rows x 32 lanes
__device__ __forceinline__ void ln_stats(const float* __restrict__ h1, const float* __restrict__ h2,
                                         float* mean, float* rstd) {
    int t = threadIdx.x, r = t >> 5, l = t & 31;
    float s = 0.f, ss = 0.f;
#pragma unroll
    for (int i = 0; i < 24; i++) {
        int e = l + i * 32;
        float v = h1[r * EE + e] + h2[r * EE + e];
        s += v; ss += v * v;
    }
#pragma unroll
    for (int m = 16; m >= 1; m >>= 1) { s += __shfl_xor(s, m); ss += __shfl_xor(ss, m); }
    if (l == 0) {
        float mu = s * (1.f / EE);
        mean[r] = mu;
        rstd[r] = rsqrtf(ss * (1.f / EE) - mu * mu + 1e-5f);
    }
}

// xl[8][KCH] x W[KCH x 64cols] -> atomicAdd out[8][64cols]
__device__ __forceinline__ void gemm_tile(const float* __restrict__ xl, const float* __restrict__ W,
                                          float* __restrict__ out, int e0, int c0, int C) {
    int t = threadIdx.x;
    int c = c0 + (t & 63);
    int r2 = (t >> 6) * 2;
    const float* Wp = W + (size_t)e0 * C + c;
    float a0 = 0.f, a1 = 0.f;
#pragma unroll
    for (int e = 0; e < KCH; e++) {
        float w = Wp[(size_t)e * C];
        a0 += xl[r2 * KCH + e] * w;
        a1 += xl[(r2 + 1) * KCH + e] * w;
    }
    atomicAdd(&out[(size_t)r2 * C + c], a0);
    atomicAdd(&out[(size_t)(r2 + 1) * C + c], a1);
}

__global__ __launch_bounds__(256, 4) void k_all(
    const int* __restrict__ ids, const int* __restrict__ posp,
    const float* __restrict__ past_k, const float* __restrict__ past_v,
    const float* __restrict__ wte, const float* __restrict__ wpe,
    const float* __restrict__ ln1g, const float* __restrict__ ln1b,
    const float* __restrict__ aw, const float* __restrict__ ab,
    const float* __restrict__ pw, const float* __restrict__ pb,
    const float* __restrict__ ln2g, const float* __restrict__ ln2b,
    const float* __restrict__ fw, const float* __restrict__ fb,
    const float* __restrict__ fpw, const float* __restrict__ fpb,
    const float* __restrict__ lnfg, const float* __restrict__ lnfb,
    float* __restrict__ logits, float* __restrict__ okeys, float* __restrict__ ovals,
    unsigned* __restrict__ bar,
    float* __restrict__ hB, float* __restrict__ hA, float* __restrict__ tmlp,
    float* __restrict__ tproj, float* __restrict__ qkv, float* __restrict__ fcbuf,
    float* __restrict__ pm, float* __restrict__ psum, float* __restrict__ po) {

    int blk = blockIdx.x, t = threadIdx.x;
    int pos = *posp, kv = pos + 1;

    // ---------------- dedicated copy blocks: stream whole KV copy, no barriers --
    if (blk >= NCOMP) {
        const f4_* kq = (const f4_*)past_k;
        const f4_* vq = (const f4_*)past_v;
        f4_* ko = (f4_*)okeys;
        f4_* vo = (f4_*)ovals;
        const size_t tot = 2 * N4HALF;
        for (size_t i = (size_t)(blk - NCOMP) * 256 + t; i < tot; i += (size_t)NCOPY * 256) {
            int row = (int)((i >> 4) & (SS - 1));
            if (row == pos) continue;
            if (i < N4HALF) {
                f4_ v = __builtin_nontemporal_load(kq + i);
                __builtin_nontemporal_store(v, ko + i);
            } else {
                size_t j = i - N4HALF;
                f4_ v = __builtin_nontemporal_load(vq + j);
                __builtin_nontemporal_store(v, vo + j);
            }
        }
        return;
    }

    // ---------------- compute blocks ----------------
    __shared__ union {
        struct { float xl[8 * KCH]; } g;
        struct { float xl[8 * EE]; } lg;
        struct { float qs[DD]; float s[CROWS]; float red[256]; float bc[2]; } a;
    } sm;
    __shared__ float s_mean[8], s_rstd[8];

    int vb = blk;

    // prologue: embed(24) | tmlp=0(24) | qkv=ab0(72)
    if (vb < 24) {
        int i = vb * 256 + t, b = i / EE, e = i % EE;
        hB[i] = wte[(size_t)ids[b] * EE + e] + wpe[(size_t)pos * EE + e];
    } else if (vb < 48) {
        tmlp[(vb - 24) * 256 + t] = 0.f;
    } else if (vb < 120) {
        int i = (vb - 48) * 256 + t;
        qkv[i] = ab[i % E3];
    }
    grid_barrier(bar);

    for (int l = 0; l < LL; l++) {
        const float* aw_l = aw + (size_t)l * EE * E3;
        const float* pw_l = pw + (size_t)l * EE * EE;
        const float* fw_l = fw + (size_t)l * EE * E4;
        const float* fpw_l = fpw + (size_t)l * E4 * EE;
        const size_t co = (size_t)l * BB * HH * SS * DD;

        // ---- P0: x=LN1(hB+tmlp); qkv += x@aw | hA=hB+tmlp | tproj=pb | fcbuf=fb
        if (vb < 432) {
            ln_stats(hB, tmlp, s_mean, s_rstd);
            __syncthreads();
            int chunk = vb / 36, colblk = vb % 36;
            int e0 = chunk * KCH, c0 = colblk * 64;
            for (int i = t; i < 8 * KCH; i += 256) {
                int b = i >> 6, ll2 = i & 63, e = e0 + ll2;
                sm.g.xl[i] = (hB[b * EE + e] + tmlp[b * EE + e] - s_mean[b]) * s_rstd[b]
                             * ln1g[l * EE + e] + ln1b[l * EE + e];
            }
            __syncthreads();
            gemm_tile(sm.g.xl, aw_l, qkv, e0, c0, E3);
        } else if (vb < 456) {
            int i = (vb - 432) * 256 + t;
            hA[i] = hB[i] + tmlp[i];
        } else if (vb < 480) {
            int i = (vb - 456) * 256 + t;
            tproj[i] = pb[l * EE + i % EE];
        } else if (vb < 576) {
            int i = (vb - 480) * 256 + t;
            fcbuf[i] = fb[(size_t)l * E4 + i % E4];
        }
        grid_barrier(bar);

        // ---- P1: attention partials (+ write new K/V row at pos)
        if (vb < BB * HH * NCH) {
            int ch = vb % NCH, bh = vb / NCH;
            int b = bh / HH, hh = bh % HH;
            int j0 = ch * CROWS;
            int idx = bh * NCH + ch;
            if (j0 >= kv) {
                if (t == 0) psum[idx] = 0.f;
            } else {
                const size_t off = co + (size_t)bh * SS * DD;
                const float* Kc = past_k + off;
                const float* Vc = past_v + off;
                const float* qn = qkv + (size_t)b * E3 + hh * DD;
                const float* kn = qn + EE;
                const float* vn = qn + 2 * EE;

                if (t < DD) sm.a.qs[t] = qn[t];
                __syncthreads();

                int row = t >> 2, q = t & 3;
                int j = j0 + row;
                float sj = 0.f;
                if (j < kv) {
                    const float4* s4 = (const float4*)(((j == pos) ? kn : (Kc + (size_t)j * DD)) + q * 16);
#pragma unroll
                    for (int i = 0; i < 4; i++) {
                        float4 k4 = s4[i];
                        int e = q * 16 + 4 * i;
                        sj += k4.x * sm.a.qs[e] + k4.y * sm.a.qs[e + 1] + k4.z * sm.a.qs[e + 2] + k4.w * sm.a.qs[e + 3];
                    }
                }
                sj += __shfl_xor(sj, 1);
                sj += __shfl_xor(sj, 2);
                if (j == pos) {
                    float4* dst = (float4*)(okeys + off + (size_t)pos * DD + q * 16);
                    const float4* sn = (const float4*)(kn + q * 16);
#pragma unroll
                    for (int i = 0; i < 4; i++) dst[i] = sn[i];
                }
                if (q == 0) sm.a.s[row] = (j < kv) ? sj * 0.125f : -INFINITY;
                __syncthreads();

                if (t < 64) {
                    float v = sm.a.s[t];
#pragma unroll
                    for (int m = 1; m <= 32; m <<= 1) v = fmaxf(v, __shfl_xor(v, m));
                    if (t == 0) sm.a.bc[0] = v;
                }
                __syncthreads();
                float m = sm.a.bc[0];
                if (t < 64) sm.a.s[t] = __expf(sm.a.s[t] - m);
                __syncthreads();
                if (t < 64) {
                    float p = sm.a.s[t];
#pragma unroll
                    for (int mm = 1; mm <= 32; mm <<= 1) p += __shfl_xor(p, mm);
                    if (t == 0) sm.a.bc[1] = p;
                }

                int d = t & 63, grp = t >> 6;
                float od = 0.f;
                for (int jj = j0 + grp; jj < j0 + CROWS; jj += 4) {
                    if (jj == pos) {
                        float vv = vn[d];
                        ovals[off + (size_t)pos * DD + d] = vv;
                        od += sm.a.s[jj - j0] * vv;
                    } else if (jj < kv) {
                        od += sm.a.s[jj - j0] * Vc[(size_t)jj * DD + d];
                    }
                }
                __syncthreads();
                sm.a.red[t] = od;
                __syncthreads();
                if (t < 64) {
                    float tt = sm.a.red[t] + sm.a.red[64 + t] + sm.a.red[128 + t] + sm.a.red[192 + t];
                    po[(size_t)idx * 64 + t] = tt;
                }
                if (t == 0) { pm[idx] = m; psum[idx] = sm.a.bc[1]; }
            }
        }
        grid_barrier(bar);

        // ---- P2: o=combine(partials); tproj += o@pw | tmlp=fpb
        if (vb < 144) {
            int chunk = vb / 12, colblk = vb % 12;
            int e0 = chunk * KCH, c0 = colblk * 64;
            for (int i = t; i < 8 * KCH; i += 256) {
                int b = i >> 6, ll2 = i & 63;
                int e = e0 + ll2;
                int hh = e >> 6, d = e & 63;
                int bh = b * HH + hh;
                float M = -INFINITY;
#pragma unroll
                for (int ch = 0; ch < NCH; ch++) {
                    int idx = bh * NCH + ch;
                    if (psum[idx] > 0.f) M = fmaxf(M, pm[idx]);
                }
                float den = 0.f, acc = 0.f;
#pragma unroll
                for (int ch = 0; ch < NCH; ch++) {
                    int idx = bh * NCH + ch;
                    float ps = psum[idx];
                    if (ps > 0.f) {
                        float f = __expf(pm[idx] - M);
                        den += ps * f;
                        acc += po[(size_t)idx * 64 + d] * f;
                    }
                }
                sm.g.xl[i] = acc / den;
            }
            __syncthreads();
            gemm_tile(sm.g.xl, pw_l, tproj, e0, c0, EE);
        } else if (vb < 168) {
            int i = (vb - 144) * 256 + t;
            tmlp[i] = fpb[l * EE + i % EE];
        }
        grid_barrier(bar);

        // ---- P3: x2=LN2(hA+tproj); fcbuf += x2@fw | hB=hA+tproj
        if (vb < 576) {
            ln_stats(hA, tproj, s_mean, s_rstd);
            __syncthreads();
            int chunk = vb / 48, colblk = vb % 48;
            int e0 = chunk * KCH, c0 = colblk * 64;
            for (int i = t; i < 8 * KCH; i += 256) {
                int b = i >> 6, ll2 = i & 63, e = e0 + ll2;
                sm.g.xl[i] = (hA[b * EE + e] + tproj[b * EE + e] - s_mean[b]) * s_rstd[b]
                             * ln2g[l * EE + e] + ln2b[l * EE + e];
            }
            __syncthreads();
            gemm_tile(sm.g.xl, fw_l, fcbuf, e0, c0, E4);
        } else if (vb < 600) {
            int i = (vb - 576) * 256 + t;
            hB[i] = hA[i] + tproj[i];
        }
        grid_barrier(bar);

        // ---- P4: tmlp += gelu(fcbuf)@fpw | qkv=ab[l+1]
        if (vb < 576) {
            int chunk = vb / 12, colblk = vb % 12;
            int e0 = chunk * KCH, c0 = colblk * 64;
            for (int i = t; i < 8 * KCH; i += 256) {
                int b = i >> 6, ll2 = i & 63;
                sm.g.xl[i] = gelu_tanh(fcbuf[(size_t)b * E4 + e0 + ll2]);
            }
            __syncthreads();
            gemm_tile(sm.g.xl, fpw_l, tmlp, e0, c0, EE);
        } else if (l < LL - 1 && vb < 648) {
            int i = (vb - 576) * 256 + t;
            qkv[i] = ab[(size_t)(l + 1) * E3 + i % E3];
        }
        grid_barrier(bar);
    }

    // ---- logits = lnf(hB+tmlp) @ wte^T
    if (vb < 786) {
        ln_stats(hB, tmlp, s_mean, s_rstd);
        __syncthreads();
        for (int i = t; i < 8 * EE; i += 256) {
            int b = i / EE, e = i % EE;
            sm.lg.xl[i] = (hB[i] + tmlp[i] - s_mean[b]) * s_rstd[b] * lnfg[e] + lnfb[e];
        }
        __syncthreads();
        int v = vb * 64 + (t >> 2);
        if (v < VV) {
            int el = t & 3;
            const float4* w = (const float4*)(wte + (size_t)v * EE);
            float acc[8] = {0, 0, 0, 0, 0, 0, 0, 0};
            for (int i = el; i < 192; i += 4) {
                float4 w4 = w[i];
#pragma unroll
                for (int b = 0; b < 8; b++) {
                    float4 xx = ((const float4*)(sm.lg.xl + b * EE))[i];
                    acc[b] += w4.x * xx.x + w4.y * xx.y + w4.z * xx.z + w4.w * xx.w;
                }
            }
#pragma unroll
            for (int b = 0; b < 8; b++) {
                acc[b] += __shfl_xor(acc[b], 1);
                acc[b] += __shfl_xor(acc[b], 2);
            }
            if (el == 0) {
#pragma unroll
                for (int b = 0; b < 8; b++) logits[(size_t)b * VV + v] = acc[b];
            }
        }
    }
}

extern "C" void kernel_launch(void* const* d_in, const int* in_sizes, int n_in,
                              void* d_out, int out_size, void* d_ws, size_t ws_size,
                              hipStream_t stream) {
    const int* ids = (const int*)d_in[0];
    const int* posp = (const int*)d_in[1];
    const float* past_k = (const float*)d_in[2];
    const float* past_v = (const float*)d_in[3];
    const float* wte = (const float*)d_in[4];
    const float* wpe = (const float*)d_in[5];
    const float* ln1g = (const float*)d_in[6];
    const float* ln1b = (const float*)d_in[7];
    const float* aw = (const float*)d_in[8];
    const float* ab = (const float*)d_in[9];
    const float* pw = (const float*)d_in[10];
    const float* pb = (const float*)d_in[11];
    const float* ln2g = (const float*)d_in[12];
    const float* ln2b = (const float*)d_in[13];
    const float* fw = (const float*)d_in[14];
    const float* fb = (const float*)d_in[15];
    const float* fpw = (const float*)d_in[16];
    const float* fpb = (const float*)d_in[17];
    const float* lnfg = (const float*)d_in[18];
    const float* lnfb = (const float*)d_in[19];

    float* logits = (float*)d_out;
    float* okeys = logits + (size_t)BB * VV;
    float* ovals = okeys + (size_t)LL * BB * HH * SS * DD;

    unsigned* bar = (unsigned*)d_ws;          // 4 KB barrier area
    float* base = (float*)((char*)d_ws + 4096);
    float* hB = base;
    float* hA = hB + BB * EE;
    float* tmlp = hA + BB * EE;
    float* tproj = tmlp + BB * EE;
    float* qkv = tproj + BB * EE;
    float* fcbuf = qkv + BB * E3;
    float* pm = fcbuf + BB * E4;
    float* psum = pm + BB * HH * NCH;
    float* po = psum + BB * HH * NCH;

    hipMemsetAsync(bar, 0, 4096, stream);
    k_all<<<GRID_, 256, 0, stream>>>(
        ids, posp, past_k, past_v, wte, wpe, ln1g, ln1b, aw, ab, pw, pb,
        ln2g, ln2b, fw, fb, fpw, fpb, lnfg, lnfb,
        logits, okeys, ovals, bar,
        hB, hA, tmlp, tproj, qkv, fcbuf, pm, psum, po);
}

// Round 7
// 2349.519 us; speedup vs baseline: 10.4675x; 1.4181x over previous
//
#include <hip/hip_runtime.h>

#define LL 12
#define BB 8
#define HH 12
#define EE 768
#define DD 64
#define SS 1024
#define VV 50257
#define E3 2304
#define E4 3072
#define GRID_ 1024
#define N4HALF 18874368ull   // float4 per KV buffer
#define SPC 32               // unsigned words per 128B cacheline

typedef float f4_ __attribute__((ext_vector_type(4)));

__device__ __forceinline__ float gelu_tanh(float v) {
    float c = 0.7978845608028654f * (v + 0.044715f * v * v * v);
    return 0.5f * v * (1.0f + tanhf(c));
}

__device__ __forceinline__ unsigned ld_at(unsigned* p) {
    return __hip_atomic_load(p, __ATOMIC_RELAXED, __HIP_MEMORY_SCOPE_AGENT);
}
__device__ __forceinline__ unsigned add_at(unsigned* p, unsigned v) {
    return __hip_atomic_fetch_add(p, v, __ATOMIC_RELAXED, __HIP_MEMORY_SCOPE_AGENT);
}
__device__ __forceinline__ void st_at(float* p, float v) {
    __hip_atomic_store(p, v, __ATOMIC_RELAXED, __HIP_MEMORY_SCOPE_AGENT);
}

// L1-only invalidate (within-XCD L2 is the coherence point for group data)
__device__ __forceinline__ void l1_inv() {
    asm volatile("buffer_inv\ns_waitcnt vmcnt(0)" ::: "memory");
}

// barrier over the group's compute blocks: atomic arrivals on 4 sub-lines, no L2 fences
__device__ __forceinline__ void gbar(unsigned* sub, unsigned rank, unsigned target) {
    __syncthreads();   // drains this block's stores into its XCD L2
    if (threadIdx.x == 0) {
        add_at(sub + (rank & 3) * SPC, 1u);
        while (ld_at(sub) + ld_at(sub + SPC) + ld_at(sub + 2 * SPC) + ld_at(sub + 3 * SPC) < target)
            __builtin_amdgcn_s_sleep(4);
    }
    __syncthreads();
    l1_inv();
}

// global barrier over all 1024 blocks (atomic-only data crosses it)
__device__ __forceinline__ void gbar_all(unsigned* sub) {
    __syncthreads();
    if (threadIdx.x == 0) {
        add_at(sub + (blockIdx.x & 3) * SPC, 1u);
        while (ld_at(sub) + ld_at(sub + SPC) + ld_at(sub + 2 * SPC) + ld_at(sub + 3 * SPC) < GRID_)
            __builtin_amdgcn_s_sleep(8);
    }
    __syncthreads();
    l1_inv();
}

// LN of (h1+h2) row (768) -> xl[0..768), full block
__device__ __forceinline__ void ln_row(const float* __restrict__ h1, const float* __restrict__ h2,
                                       const float* __restrict__ gg, const float* __restrict__ bb,
                                       float* xl, float* red, float* bcv) {
    int t = threadIdx.x;
    float v0 = h1[t] + h2[t];
    float v1 = h1[t + 256] + h2[t + 256];
    float v2 = h1[t + 512] + h2[t + 512];
    red[t] = v0 + v1 + v2; __syncthreads();
    for (int st = 128; st; st >>= 1) { if (t < st) red[t] += red[t + st]; __syncthreads(); }
    if (t == 0) bcv[0] = red[0] * (1.f / EE);
    __syncthreads();
    float mu = bcv[0];
    float d0 = v0 - mu, d1 = v1 - mu, d2 = v2 - mu;
    __syncthreads();
    red[t] = d0 * d0 + d1 * d1 + d2 * d2; __syncthreads();
    for (int st = 128; st; st >>= 1) { if (t < st) red[t] += red[t + st]; __syncthreads(); }
    if (t == 0) bcv[1] = rsqrtf(red[0] * (1.f / EE) + 1e-5f);
    __syncthreads();
    float rs = bcv[1];
    xl[t] = d0 * rs * gg[t] + bb[t];
    xl[t + 256] = d1 * rs * gg[t + 256] + bb[t + 256];
    xl[t + 512] = d2 * rs * gg[t + 512] + bb[t + 512];
    __syncthreads();
}

// 32 output cols, full-K dot: out[c0+j] = bias[c0+j] + xl[0..K) . W[:,c0+j]
__device__ __forceinline__ void gemm32(const float* xl, int K, const float* __restrict__ W, int ldw,
                                       const float* __restrict__ bias, float* __restrict__ out,
                                       int c0, float* red) {
    int t = threadIdx.x;
    int cc = c0 + (t & 31), ks = t >> 5;
    int kl = K >> 3;
    const float* Wp = W + (size_t)(ks * kl) * ldw + cc;
    const float* xp = xl + ks * kl;
    float acc = 0.f;
    for (int e = 0; e < kl; e++) acc += xp[e] * Wp[(size_t)e * ldw];
    red[t] = acc; __syncthreads();
    if (t < 32) {
        float a = bias[c0 + t];
#pragma unroll
        for (int k2 = 0; k2 < 8; k2++) a += red[k2 * 32 + t];
        out[c0 + t] = a;
    }
    __syncthreads();
}

__global__ __launch_bounds__(256, 4) void k_all(
    const int* __restrict__ ids, const int* __restrict__ posp,
    const float* __restrict__ past_k, const float* __restrict__ past_v,
    const float* __restrict__ wte, const float* __restrict__ wpe,
    const float* __restrict__ ln1g, const float* __restrict__ ln1b,
    const float* __restrict__ aw, const float* __restrict__ ab,
    const float* __restrict__ pw, const float* __restrict__ pb,
    const float* __restrict__ ln2g, const float* __restrict__ ln2b,
    const float* __restrict__ fw, const float* __restrict__ fb,
    const float* __restrict__ fpw, const float* __restrict__ fpb,
    const float* __restrict__ lnfg, const float* __restrict__ lnfb,
    float* __restrict__ logits, float* __restrict__ okeys, float* __restrict__ ovals,
    unsigned* __restrict__ ctrl,
    float* __restrict__ hB, float* __restrict__ hA, float* __restrict__ tmlp,
    float* __restrict__ tproj, float* __restrict__ qkv, float* __restrict__ fcbuf,
    float* __restrict__ pm, float* __restrict__ psum, float* __restrict__ po,
    float* __restrict__ xf) {

    int t = threadIdx.x;
    int pos = *posp, kv = pos + 1;

    __shared__ __align__(16) float xl[6144];
    __shared__ float red[256];
    __shared__ float bcv[4];
    __shared__ unsigned shu[4];

    // ---- registration: group = physical XCD ----
    if (t == 0) {
        unsigned xcc;
        asm volatile("s_getreg_b32 %0, hwreg(HW_REG_XCC_ID)" : "=s"(xcc));
        unsigned gg = xcc & 7u;
        shu[0] = gg;
        shu[1] = add_at(ctrl + gg * SPC, 1u);  // rank within group
    }
    __syncthreads();
    unsigned g = shu[0], rank = shu[1];
    gbar_all(ctrl + 8 * SPC);                  // stage 1: all registered
    if (t == 0) shu[2] = ld_at(ctrl + g * SPC);
    __syncthreads();
    unsigned sg = shu[2];
    unsigned c = sg - sg / 4;                  // compute members; rest copy
    if (c == 0 || c > sg) c = sg;
    bool isComp = (rank < c);
    if (t == 0 && !isComp) shu[3] = add_at(ctrl + 16 * SPC, 1u);   // copy rank
    __syncthreads();
    unsigned crank = shu[3];
    gbar_all(ctrl + 12 * SPC);                 // stage 2: copy ranks final
    if (t == 0) shu[3] = ld_at(ctrl + 16 * SPC);
    __syncthreads();
    unsigned ctot = shu[3];

    if (isComp) {
        unsigned* gq = ctrl + 1024 + g * 4 * SPC;
        unsigned nbar = 0;
        float* hBg = hB + g * EE;
        float* hAg = hA + g * EE;
        float* tmlpg = tmlp + g * EE;
        float* tprojg = tproj + g * EE;
        float* qkvg = qkv + g * E3;
        float* fcbufg = fcbuf + g * E4;

        // prologue: embed row g, tmlp row g = 0
        if (rank == 0) {
            for (int i = t; i < EE; i += 256) {
                hBg[i] = wte[(size_t)ids[g] * EE + i] + wpe[(size_t)pos * EE + i];
                tmlpg[i] = 0.f;
            }
        }
        nbar++; gbar(gq, rank, c * nbar);

        for (int l = 0; l < LL; l++) {
            const float* aw_l = aw + (size_t)l * EE * E3;
            const float* ab_l = ab + (size_t)l * E3;
            const float* pw_l = pw + (size_t)l * EE * EE;
            const float* pb_l = pb + (size_t)l * EE;
            const float* fw_l = fw + (size_t)l * EE * E4;
            const float* fb_l = fb + (size_t)l * E4;
            const float* fpw_l = fpw + (size_t)l * E4 * EE;
            const float* fpb_l = fpb + (size_t)l * EE;

            // ---- Ph0: x = LN1(hB+tmlp); qkv = x@aw + ab ; hA = hB+tmlp
            ln_row(hBg, tmlpg, ln1g + l * EE, ln1b + l * EE, xl, red, bcv);
            for (unsigned u = rank; u < 73; u += c) {
                if (u < 72) gemm32(xl, EE, aw_l, E3, ab_l, qkvg, u * 32, red);
                else { for (int i = t; i < EE; i += 256) hAg[i] = hBg[i] + tmlpg[i]; __syncthreads(); }
            }
            nbar++; gbar(gq, rank, c * nbar);

            // ---- Ph1: attention partials (+ write new K/V row at pos)
            for (unsigned u = rank; u < 108; u += c) {
                int hh = u / 9, ch = u % 9;
                int j0 = ch * 64;
                int idx = (g * HH + hh) * 9 + ch;
                if (j0 >= kv) { if (t == 0) psum[idx] = 0.f; continue; }
                const size_t off = ((size_t)l * BB * HH + g * HH + hh) * SS * DD;
                const float* Kc = past_k + off;
                const float* Vc = past_v + off;
                const float* qn = qkvg + hh * DD;
                const float* kn = qn + EE;
                const float* vn = qn + 2 * EE;
                float* qs = xl;        // [0,64)
                float* sv = xl + 64;   // [64,128)
                if (t < DD) qs[t] = qn[t];
                __syncthreads();
                int row = t >> 2, q = t & 3;
                int j = j0 + row;
                float sj = 0.f;
                if (j < kv) {
                    const float4* s4 = (const float4*)(((j == pos) ? kn : (Kc + (size_t)j * DD)) + q * 16);
#pragma unroll
                    for (int i = 0; i < 4; i++) {
                        float4 k4 = s4[i];
                        int e = q * 16 + 4 * i;
                        sj += k4.x * qs[e] + k4.y * qs[e + 1] + k4.z * qs[e + 2] + k4.w * qs[e + 3];
                    }
                }
                sj += __shfl_xor(sj, 1);
                sj += __shfl_xor(sj, 2);
                if (j == pos) {
                    float4* dst = (float4*)(okeys + off + (size_t)pos * DD + q * 16);
                    const float4* sn = (const float4*)(kn + q * 16);
#pragma unroll
                    for (int i = 0; i < 4; i++) dst[i] = sn[i];
                }
                if (q == 0) sv[row] = (j < kv) ? sj * 0.125f : -INFINITY;
                __syncthreads();
                if (t < 64) {
                    float v = sv[t];
#pragma unroll
                    for (int m = 1; m <= 32; m <<= 1) v = fmaxf(v, __shfl_xor(v, m));
                    if (t == 0) bcv[0] = v;
                }
                __syncthreads();
                float m = bcv[0];
                if (t < 64) sv[t] = __expf(sv[t] - m);
                __syncthreads();
                if (t < 64) {
                    float p = sv[t];
#pragma unroll
                    for (int mm = 1; mm <= 32; mm <<= 1) p += __shfl_xor(p, mm);
                    if (t == 0) bcv[1] = p;
                }
                int d = t & 63, grp = t >> 6;
                float od = 0.f;
                for (int jj = j0 + grp; jj < j0 + 64; jj += 4) {
                    if (jj == pos) {
                        float vv = vn[d];
                        ovals[off + (size_t)pos * DD + d] = vv;
                        od += sv[jj - j0] * vv;
                    } else if (jj < kv) {
                        od += sv[jj - j0] * Vc[(size_t)jj * DD + d];
                    }
                }
                __syncthreads();
                red[t] = od; __syncthreads();
                if (t < 64) {
                    float tt = red[t] + red[64 + t] + red[128 + t] + red[192 + t];
                    po[(size_t)idx * 64 + t] = tt;
                }
                if (t == 0) { pm[idx] = m; psum[idx] = bcv[1]; }
                __syncthreads();
            }
            nbar++; gbar(gq, rank, c * nbar);

            // ---- Ph2: o = combine(partials); tproj = o@pw + pb
            for (int i = t; i < EE; i += 256) {
                int hh = i >> 6, d = i & 63;
                int base = (g * HH + hh) * 9;
                float M = -INFINITY;
#pragma unroll
                for (int ch = 0; ch < 9; ch++) if (psum[base + ch] > 0.f) M = fmaxf(M, pm[base + ch]);
                float den = 0.f, acc = 0.f;
#pragma unroll
                for (int ch = 0; ch < 9; ch++) {
                    float ps = psum[base + ch];
                    if (ps > 0.f) {
                        float f = __expf(pm[base + ch] - M);
                        den += ps * f;
                        acc += po[(size_t)(base + ch) * 64 + d] * f;
                    }
                }
                xl[i] = acc / den;
            }
            __syncthreads();
            for (unsigned u = rank; u < 24; u += c)
                gemm32(xl, EE, pw_l, EE, pb_l, tprojg, u * 32, red);
            nbar++; gbar(gq, rank, c * nbar);

            // ---- Ph3: x2 = LN2(hA+tproj); fcbuf = x2@fw + fb ; hB = hA+tproj
            ln_row(hAg, tprojg, ln2g + l * EE, ln2b + l * EE, xl, red, bcv);
            for (unsigned u = rank; u < 97; u += c) {
                if (u < 96) gemm32(xl, EE, fw_l, E4, fb_l, fcbufg, u * 32, red);
                else { for (int i = t; i < EE; i += 256) hBg[i] = hAg[i] + tprojg[i]; __syncthreads(); }
            }
            nbar++; gbar(gq, rank, c * nbar);

            // ---- Ph4: tmlp = gelu(fcbuf)@fpw + fpb
            for (int i = t; i < E4; i += 256) xl[i] = gelu_tanh(fcbufg[i]);
            __syncthreads();
            for (unsigned u = rank; u < 24; u += c)
                gemm32(xl, E4, fpw_l, EE, fpb_l, tmlpg, u * 32, red);
            nbar++; gbar(gq, rank, c * nbar);
        }

        // ---- final LN -> xf row g (published via device-scope atomic stores)
        if (rank == 0) {
            ln_row(hBg, tmlpg, lnfg, lnfb, xl, red, bcv);
            for (int i = t; i < EE; i += 256) st_at(&xf[g * EE + i], xl[i]);
        }
    } else {
        // ---- copy blocks: stream whole KV copy (skip row pos), fence-free
        const f4_* kq = (const f4_*)past_k;
        const f4_* vq = (const f4_*)past_v;
        f4_* ko = (f4_*)okeys;
        f4_* vo = (f4_*)ovals;
        const size_t tot = 2 * N4HALF;
        for (size_t i = (size_t)crank * 256 + t; i < tot; i += (size_t)ctot * 256) {
            int row = (int)((i >> 4) & (SS - 1));
            if (row == pos) continue;
            if (i < N4HALF) {
                f4_ v = __builtin_nontemporal_load(kq + i);
                __builtin_nontemporal_store(v, ko + i);
            } else {
                size_t jdx = i - N4HALF;
                f4_ v = __builtin_nontemporal_load(vq + jdx);
                __builtin_nontemporal_store(v, vo + jdx);
            }
        }
    }

    // ---- global barrier, then logits = xf @ wte^T over all blocks
    gbar_all(ctrl + 17 * SPC);

    int vb = blockIdx.x;
    if (vb < 786) {
        for (int i = t; i < BB * EE; i += 256) xl[i] = xf[i];
        __syncthreads();
        int v = vb * 64 + (t >> 2);
        if (v < VV) {
            int el = t & 3;
            const float4* w = (const float4*)(wte + (size_t)v * EE);
            float acc[8] = {0, 0, 0, 0, 0, 0, 0, 0};
            for (int i = el; i < 192; i += 4) {
                float4 w4 = w[i];
#pragma unroll
                for (int b = 0; b < 8; b++) {
                    float4 xx = ((const float4*)(xl + b * EE))[i];
                    acc[b] += w4.x * xx.x + w4.y * xx.y + w4.z * xx.z + w4.w * xx.w;
                }
            }
#pragma unroll
            for (int b = 0; b < 8; b++) {
                acc[b] += __shfl_xor(acc[b], 1);
                acc[b] += __shfl_xor(acc[b], 2);
            }
            if (el == 0) {
#pragma unroll
                for (int b = 0; b < 8; b++) logits[(size_t)b * VV + v] = acc[b];
            }
        }
    }
}

extern "C" void kernel_launch(void* const* d_in, const int* in_sizes, int n_in,
                              void* d_out, int out_size, void* d_ws, size_t ws_size,
                              hipStream_t stream) {
    const int* ids = (const int*)d_in[0];
    const int* posp = (const int*)d_in[1];
    const float* past_k = (const float*)d_in[2];
    const float* past_v = (const float*)d_in[3];
    const float* wte = (const float*)d_in[4];
    const float* wpe = (const float*)d_in[5];
    const float* ln1g = (const float*)d_in[6];
    const float* ln1b = (const float*)d_in[7];
    const float* aw = (const float*)d_in[8];
    const float* ab = (const float*)d_in[9];
    const float* pw = (const float*)d_in[10];
    const float* pb = (const float*)d_in[11];
    const float* ln2g = (const float*)d_in[12];
    const float* ln2b = (const float*)d_in[13];
    const float* fw = (const float*)d_in[14];
    const float* fb = (const float*)d_in[15];
    const float* fpw = (const float*)d_in[16];
    const float* fpb = (const float*)d_in[17];
    const float* lnfg = (const float*)d_in[18];
    const float* lnfb = (const float*)d_in[19];

    float* logits = (float*)d_out;
    float* okeys = logits + (size_t)BB * VV;
    float* ovals = okeys + (size_t)LL * BB * HH * SS * DD;

    unsigned* ctrl = (unsigned*)d_ws;                 // 8 KB control area
    float* base = (float*)((char*)d_ws + 8192);
    float* hB = base;                  // 8*768
    float* hA = hB + BB * EE;
    float* tmlp = hA + BB * EE;
    float* tproj = tmlp + BB * EE;
    float* qkv = tproj + BB * EE;      // 8*2304
    float* fcbuf = qkv + BB * E3;      // 8*3072
    float* pm = fcbuf + BB * E4;       // 864
    float* psum = pm + BB * HH * 9;    // 864
    float* po = psum + BB * HH * 9;    // 864*64
    float* xf = po + (size_t)BB * HH * 9 * 64;  // 8*768

    hipMemsetAsync(ctrl, 0, 8192, stream);
    k_all<<<GRID_, 256, 0, stream>>>(
        ids, posp, past_k, past_v, wte, wpe, ln1g, ln1b, aw, ab, pw, pb,
        ln2g, ln2b, fw, fb, fpw, fpb, lnfg, lnfb,
        logits, okeys, ovals, ctrl,
        hB, hA, tmlp, tproj, qkv, fcbuf, pm, psum, po, xf);
}

// Round 8
// 1768.733 us; speedup vs baseline: 13.9047x; 1.3284x over previous
//
#include <hip/hip_runtime.h>

#define LL 12
#define BB 8
#define HH 12
#define EE 768
#define DD 64
#define SS 1024
#define VV 50257
#define E3 2304
#define E4 3072
#define GRID_ 1024
#define N4HALF 18874368ull   // float4 per KV buffer
#define SPC 32               // unsigned words per 128B cacheline
#define CROWS 72
#define NCHU 8               // covers kv <= 576

typedef float f4_ __attribute__((ext_vector_type(4)));

__device__ __forceinline__ float gelu_tanh(float v) {
    float c = 0.7978845608028654f * (v + 0.044715f * v * v * v);
    return 0.5f * v * (1.0f + tanhf(c));
}

// ---- agent-scope atomics (cross-XCD; used only for registration/final) ----
__device__ __forceinline__ unsigned ld_at(unsigned* p) {
    return __hip_atomic_load(p, __ATOMIC_RELAXED, __HIP_MEMORY_SCOPE_AGENT);
}
__device__ __forceinline__ unsigned add_at(unsigned* p, unsigned v) {
    return __hip_atomic_fetch_add(p, v, __ATOMIC_RELAXED, __HIP_MEMORY_SCOPE_AGENT);
}
__device__ __forceinline__ void st_sys(float* p, float v) {
    __hip_atomic_store(p, v, __ATOMIC_RELAXED, __HIP_MEMORY_SCOPE_SYSTEM);
}

// ---- XCD-L2-local atomic add-with-return: no sc1 -> executes in local L2 ----
__device__ __forceinline__ unsigned l2_add(unsigned* p, unsigned v) {
    unsigned old;
    asm volatile("s_waitcnt vmcnt(0)\n\t"
                 "global_atomic_add %0, %1, %2, off sc0\n\t"
                 "s_waitcnt vmcnt(0)"
                 : "=&v"(old) : "v"(p), "v"(v) : "memory");
    return old;
}

// L1-only invalidate (the XCD L2 is the coherence point for group data)
__device__ __forceinline__ void l1_inv() {
    asm volatile("buffer_inv\ns_waitcnt vmcnt(0)" ::: "memory");
}

// group barrier: single L2-local arrival counter + 4 mirrored L2-local flags
// gq line layout: cnt at +0, flag mirror k at +(4+k)*SPC
__device__ __forceinline__ void gbar(unsigned* gq, unsigned rank, unsigned c, unsigned nbar) {
    __syncthreads();   // drains vmcnt: this block's stores are in the XCD L2
    if (threadIdx.x == 0) {
        unsigned old = l2_add(gq, 1u);
        if (old + 1u == c * nbar) {
#pragma unroll
            for (int k = 0; k < 4; k++) l2_add(gq + (4 + k) * SPC, 1u);
        } else {
            unsigned* f = gq + (4 + (rank & 3u)) * SPC;
            while (l2_add(f, 0u) < nbar) __builtin_amdgcn_s_sleep(8);
        }
    }
    __syncthreads();
    l1_inv();
}

// global barrier over all blocks (agent scope; used 4x total)
__device__ __forceinline__ void gbar_all(unsigned* sub) {
    __syncthreads();
    if (threadIdx.x == 0) {
        add_at(sub + (blockIdx.x & 3) * SPC, 1u);
        while (ld_at(sub) + ld_at(sub + SPC) + ld_at(sub + 2 * SPC) + ld_at(sub + 3 * SPC) < GRID_)
            __builtin_amdgcn_s_sleep(8);
    }
    __syncthreads();
    l1_inv();
}

// LN of (h1+h2) row (768) -> xl[0..768)
__device__ __forceinline__ void ln_row(const float* __restrict__ h1, const float* __restrict__ h2,
                                       const float* __restrict__ gg, const float* __restrict__ bb,
                                       float* xl, float* red, float* bcv) {
    int t = threadIdx.x;
    float v0 = h1[t] + h2[t];
    float v1 = h1[t + 256] + h2[t + 256];
    float v2 = h1[t + 512] + h2[t + 512];
    float s = v0 + v1 + v2, ss = v0 * v0 + v1 * v1 + v2 * v2;
#pragma unroll
    for (int m = 32; m >= 1; m >>= 1) { s += __shfl_xor(s, m); ss += __shfl_xor(ss, m); }
    int w = t >> 6;
    if ((t & 63) == 0) { red[w] = s; red[8 + w] = ss; }
    __syncthreads();
    if (t == 0) {
        float S = red[0] + red[1] + red[2] + red[3];
        float Q = red[8] + red[9] + red[10] + red[11];
        float mu = S * (1.f / EE);
        bcv[0] = mu;
        bcv[1] = rsqrtf(Q * (1.f / EE) - mu * mu + 1e-5f);
    }
    __syncthreads();
    float mu = bcv[0], rs = bcv[1];
    xl[t] = (v0 - mu) * rs * gg[t] + bb[t];
    xl[t + 256] = (v1 - mu) * rs * gg[t + 256] + bb[t + 256];
    xl[t + 512] = (v2 - mu) * rs * gg[t + 512] + bb[t + 512];
    __syncthreads();
}

// NC output cols, full-K dot: out[c0+j] = bias[c0+j] + xl[0..K) . W[:,c0+j]
template <int NC>
__device__ __forceinline__ void gemmN(const float* xl, int K, const float* __restrict__ W, int ldw,
                                      const float* __restrict__ bias, float* __restrict__ out,
                                      int c0, float* red) {
    constexpr int NS = 256 / NC;
    int t = threadIdx.x;
    int cc = c0 + (t % NC), ks = t / NC;
    int kl = K / NS;
    const float* Wp = W + (size_t)(ks * kl) * ldw + cc;
    const float* xp = xl + ks * kl;
    float acc = 0.f;
    for (int e = 0; e < kl; e++) acc += xp[e] * Wp[(size_t)e * ldw];
    red[t] = acc; __syncthreads();
    if (t < NC) {
        float a = bias[c0 + t];
#pragma unroll
        for (int k2 = 0; k2 < NS; k2++) a += red[k2 * NC + t];
        out[c0 + t] = a;
    }
    __syncthreads();
}

__global__ __launch_bounds__(256, 4) void k_all(
    const int* __restrict__ ids, const int* __restrict__ posp,
    const float* __restrict__ past_k, const float* __restrict__ past_v,
    const float* __restrict__ wte, const float* __restrict__ wpe,
    const float* __restrict__ ln1g, const float* __restrict__ ln1b,
    const float* __restrict__ aw, const float* __restrict__ ab,
    const float* __restrict__ pw, const float* __restrict__ pb,
    const float* __restrict__ ln2g, const float* __restrict__ ln2b,
    const float* __restrict__ fw, const float* __restrict__ fb,
    const float* __restrict__ fpw, const float* __restrict__ fpb,
    const float* __restrict__ lnfg, const float* __restrict__ lnfb,
    float* __restrict__ logits, float* __restrict__ okeys, float* __restrict__ ovals,
    unsigned* __restrict__ ctrl,
    float* __restrict__ hB, float* __restrict__ hA, float* __restrict__ tmlp,
    float* __restrict__ tproj, float* __restrict__ qkv, float* __restrict__ fcbuf,
    float* __restrict__ pm, float* __restrict__ psum, float* __restrict__ po,
    float* __restrict__ xf) {

    int t = threadIdx.x;
    int pos = *posp, kv = pos + 1;

    __shared__ __align__(16) float xl[6144];
    __shared__ float red[256];
    __shared__ float bcv[4];
    __shared__ unsigned shu[4];

    // ---- registration: group = physical XCD ----
    if (t == 0) {
        unsigned xcc;
        asm volatile("s_getreg_b32 %0, hwreg(HW_REG_XCC_ID)" : "=s"(xcc));
        unsigned gg = xcc & 7u;
        shu[0] = gg;
        shu[1] = add_at(ctrl + gg * SPC, 1u);  // rank within group
    }
    __syncthreads();
    unsigned g = shu[0], rank = shu[1];
    gbar_all(ctrl + 8 * SPC);                  // stage 1: all registered
    if (t == 0) shu[2] = ld_at(ctrl + g * SPC);
    __syncthreads();
    unsigned sg = shu[2];
    unsigned c = sg - sg / 4;                  // compute members; rest copy
    if (c == 0 || c > sg) c = sg;
    bool isComp = (rank < c);
    if (t == 0 && !isComp) shu[3] = add_at(ctrl + 16 * SPC, 1u);   // copy rank
    __syncthreads();
    unsigned crank = shu[3];
    gbar_all(ctrl + 12 * SPC);                 // stage 2: copy ranks final
    if (t == 0) shu[3] = ld_at(ctrl + 16 * SPC);
    __syncthreads();
    unsigned ctot = shu[3];

    if (isComp) {
        unsigned* gq = ctrl + 1024 + g * 8 * SPC;   // L2-local barrier lines for group g
        unsigned nbar = 0;
        float* hBg = hB + g * EE;
        float* hAg = hA + g * EE;
        float* tmlpg = tmlp + g * EE;
        float* tprojg = tproj + g * EE;
        float* qkvg = qkv + g * E3;
        float* fcbufg = fcbuf + g * E4;

        // prologue: embed row g, tmlp row g = 0
        if (rank == 0) {
            for (int i = t; i < EE; i += 256) {
                hBg[i] = wte[(size_t)ids[g] * EE + i] + wpe[(size_t)pos * EE + i];
                tmlpg[i] = 0.f;
            }
        }
        nbar++; gbar(gq, rank, c, nbar);

        for (int l = 0; l < LL; l++) {
            const float* aw_l = aw + (size_t)l * EE * E3;
            const float* ab_l = ab + (size_t)l * E3;
            const float* pw_l = pw + (size_t)l * EE * EE;
            const float* pb_l = pb + (size_t)l * EE;
            const float* fw_l = fw + (size_t)l * EE * E4;
            const float* fb_l = fb + (size_t)l * E4;
            const float* fpw_l = fpw + (size_t)l * E4 * EE;
            const float* fpb_l = fpb + (size_t)l * EE;

            // ---- Ph0: x = LN1(hB+tmlp); qkv = x@aw + ab ; hA = hB+tmlp
            ln_row(hBg, tmlpg, ln1g + l * EE, ln1b + l * EE, xl, red, bcv);
            for (unsigned u = rank; u < 73; u += c) {
                if (u < 72) gemmN<32>(xl, EE, aw_l, E3, ab_l, qkvg, u * 32, red);
                else { for (int i = t; i < EE; i += 256) hAg[i] = hBg[i] + tmlpg[i]; __syncthreads(); }
            }
            nbar++; gbar(gq, rank, c, nbar);

            // ---- Ph1: attention partials (+ write new K/V row at pos), 96 units
            for (unsigned u = rank; u < HH * NCHU; u += c) {
                int hh = u / NCHU, ch = u % NCHU;
                int j0 = ch * CROWS;
                int idx = (g * HH + hh) * NCHU + ch;
                if (j0 >= kv) { if (t == 0) psum[idx] = 0.f; continue; }
                const size_t off = ((size_t)l * BB * HH + g * HH + hh) * SS * DD;
                const float* Kc = past_k + off;
                const float* Vc = past_v + off;
                const float* qn = qkvg + hh * DD;
                const float* kn = qn + EE;
                const float* vn = qn + 2 * EE;
                float* qs = xl;          // [0,64)
                float* sv = xl + 64;     // [64,64+CROWS)
                if (t < DD) qs[t] = qn[t];
                __syncthreads();

                // K pass: 2 threads per row (threads 0..143)
                if (t < 2 * CROWS) {
                    int row = t >> 1, half = t & 1;
                    int j = j0 + row;
                    float sj = 0.f;
                    if (j < kv) {
                        const float4* s4 = (const float4*)(((j == pos) ? kn : (Kc + (size_t)j * DD)) + half * 32);
#pragma unroll
                        for (int i = 0; i < 8; i++) {
                            float4 k4 = s4[i];
                            int e = half * 32 + 4 * i;
                            sj += k4.x * qs[e] + k4.y * qs[e + 1] + k4.z * qs[e + 2] + k4.w * qs[e + 3];
                        }
                    }
                    sj += __shfl_xor(sj, 1);
                    if (j == pos) {
                        float4* dst = (float4*)(okeys + off + (size_t)pos * DD + half * 32);
                        const float4* sn = (const float4*)(kn + half * 32);
#pragma unroll
                        for (int i = 0; i < 8; i++) dst[i] = sn[i];
                    }
                    if (half == 0) sv[row] = (j < kv) ? sj * 0.125f : -INFINITY;
                }
                __syncthreads();

                red[t] = (t < CROWS) ? sv[t] : -INFINITY;
                __syncthreads();
                for (int st = 128; st >= 1; st >>= 1) { if (t < st) red[t] = fmaxf(red[t], red[t + st]); __syncthreads(); }
                if (t == 0) bcv[0] = red[0];
                __syncthreads();
                float m = bcv[0];
                if (t < CROWS) sv[t] = __expf(sv[t] - m);
                __syncthreads();
                red[t] = (t < CROWS) ? sv[t] : 0.f;
                __syncthreads();
                for (int st = 128; st >= 1; st >>= 1) { if (t < st) red[t] += red[t + st]; __syncthreads(); }
                if (t == 0) bcv[1] = red[0];
                __syncthreads();

                // V pass
                int d = t & 63, grp = t >> 6;
                float od = 0.f;
                for (int jj = j0 + grp; jj < j0 + CROWS; jj += 4) {
                    if (jj == pos) {
                        float vv = vn[d];
                        ovals[off + (size_t)pos * DD + d] = vv;
                        od += sv[jj - j0] * vv;
                    } else if (jj < kv) {
                        od += sv[jj - j0] * Vc[(size_t)jj * DD + d];
                    }
                }
                __syncthreads();
                red[t] = od; __syncthreads();
                if (t < 64) {
                    float tt = red[t] + red[64 + t] + red[128 + t] + red[192 + t];
                    po[(size_t)idx * 64 + t] = tt;
                }
                if (t == 0) { pm[idx] = m; psum[idx] = bcv[1]; }
                __syncthreads();
            }
            nbar++; gbar(gq, rank, c, nbar);

            // ---- Ph2: o = combine(partials); tproj = o@pw + pb (96 units x 8 cols)
            for (int i = t; i < EE; i += 256) {
                int hh = i >> 6, d = i & 63;
                int base = (g * HH + hh) * NCHU;
                float M = -INFINITY;
#pragma unroll
                for (int ch = 0; ch < NCHU; ch++) if (psum[base + ch] > 0.f) M = fmaxf(M, pm[base + ch]);
                float den = 0.f, acc = 0.f;
#pragma unroll
                for (int ch = 0; ch < NCHU; ch++) {
                    float ps = psum[base + ch];
                    if (ps > 0.f) {
                        float f = __expf(pm[base + ch] - M);
                        den += ps * f;
                        acc += po[(size_t)(base + ch) * 64 + d] * f;
                    }
                }
                xl[i] = acc / den;
            }
            __syncthreads();
            for (unsigned u = rank; u < 96; u += c)
                gemmN<8>(xl, EE, pw_l, EE, pb_l, tprojg, u * 8, red);
            nbar++; gbar(gq, rank, c, nbar);

            // ---- Ph3: x2 = LN2(hA+tproj); fcbuf = x2@fw + fb ; hB = hA+tproj (97 units)
            ln_row(hAg, tprojg, ln2g + l * EE, ln2b + l * EE, xl, red, bcv);
            for (unsigned u = rank; u < 97; u += c) {
                if (u < 96) gemmN<32>(xl, EE, fw_l, E4, fb_l, fcbufg, u * 32, red);
                else { for (int i = t; i < EE; i += 256) hBg[i] = hAg[i] + tprojg[i]; __syncthreads(); }
            }
            nbar++; gbar(gq, rank, c, nbar);

            // ---- Ph4: tmlp = gelu(fcbuf)@fpw + fpb (96 units x 8 cols, K=3072)
            for (int i = t; i < E4; i += 256) xl[i] = gelu_tanh(fcbufg[i]);
            __syncthreads();
            for (unsigned u = rank; u < 96; u += c)
                gemmN<8>(xl, E4, fpw_l, EE, fpb_l, tmlpg, u * 8, red);
            nbar++; gbar(gq, rank, c, nbar);
        }

        // ---- final LN -> xf row g (published device-wide)
        if (rank == 0) {
            ln_row(hBg, tmlpg, lnfg, lnfb, xl, red, bcv);
            for (int i = t; i < EE; i += 256) st_sys(&xf[g * EE + i], xl[i]);
        }
    } else {
        // ---- copy blocks: stream whole KV copy (skip row pos), fence-free
        const f4_* kq = (const f4_*)past_k;
        const f4_* vq = (const f4_*)past_v;
        f4_* ko = (f4_*)okeys;
        f4_* vo = (f4_*)ovals;
        const size_t tot = 2 * N4HALF;
        for (size_t i = (size_t)crank * 256 + t; i < tot; i += (size_t)ctot * 256) {
            int row = (int)((i >> 4) & (SS - 1));
            if (row == pos) continue;
            if (i < N4HALF) {
                f4_ v = __builtin_nontemporal_load(kq + i);
                __builtin_nontemporal_store(v, ko + i);
            } else {
                size_t jdx = i - N4HALF;
                f4_ v = __builtin_nontemporal_load(vq + jdx);
                __builtin_nontemporal_store(v, vo + jdx);
            }
        }
    }

    // ---- global barrier, then logits = xf @ wte^T over all blocks
    gbar_all(ctrl + 17 * SPC);

    int vb = blockIdx.x;
    if (vb < 786) {
        for (int i = t; i < BB * EE; i += 256) xl[i] = xf[i];
        __syncthreads();
        int v = vb * 64 + (t >> 2);
        if (v < VV) {
            int el = t & 3;
            const float4* w = (const float4*)(wte + (size_t)v * EE);
            float acc[8] = {0, 0, 0, 0, 0, 0, 0, 0};
            for (int i = el; i < 192; i += 4) {
                float4 w4 = w[i];
#pragma unroll
                for (int b = 0; b < 8; b++) {
                    float4 xx = ((const float4*)(xl + b * EE))[i];
                    acc[b] += w4.x * xx.x + w4.y * xx.y + w4.z * xx.z + w4.w * xx.w;
                }
            }
#pragma unroll
            for (int b = 0; b < 8; b++) {
                acc[b] += __shfl_xor(acc[b], 1);
                acc[b] += __shfl_xor(acc[b], 2);
            }
            if (el == 0) {
#pragma unroll
                for (int b = 0; b < 8; b++) logits[(size_t)b * VV + v] = acc[b];
            }
        }
    }
}

extern "C" void kernel_launch(void* const* d_in, const int* in_sizes, int n_in,
                              void* d_out, int out_size, void* d_ws, size_t ws_size,
                              hipStream_t stream) {
    const int* ids = (const int*)d_in[0];
    const int* posp = (const int*)d_in[1];
    const float* past_k = (const float*)d_in[2];
    const float* past_v = (const float*)d_in[3];
    const float* wte = (const float*)d_in[4];
    const float* wpe = (const float*)d_in[5];
    const float* ln1g = (const float*)d_in[6];
    const float* ln1b = (const float*)d_in[7];
    const float* aw = (const float*)d_in[8];
    const float* ab = (const float*)d_in[9];
    const float* pw = (const float*)d_in[10];
    const float* pb = (const float*)d_in[11];
    const float* ln2g = (const float*)d_in[12];
    const float* ln2b = (const float*)d_in[13];
    const float* fw = (const float*)d_in[14];
    const float* fb = (const float*)d_in[15];
    const float* fpw = (const float*)d_in[16];
    const float* fpb = (const float*)d_in[17];
    const float* lnfg = (const float*)d_in[18];
    const float* lnfb = (const float*)d_in[19];

    float* logits = (float*)d_out;
    float* okeys = logits + (size_t)BB * VV;
    float* ovals = okeys + (size_t)LL * BB * HH * SS * DD;

    unsigned* ctrl = (unsigned*)d_ws;                 // 16 KB control area
    float* base = (float*)((char*)d_ws + 16384);
    float* hB = base;                  // 8*768
    float* hA = hB + BB * EE;
    float* tmlp = hA + BB * EE;
    float* tproj = tmlp + BB * EE;
    float* qkv = tproj + BB * EE;      // 8*2304
    float* fcbuf = qkv + BB * E3;      // 8*3072
    float* pm = fcbuf + BB * E4;       // 8*12*8
    float* psum = pm + BB * HH * NCHU;
    float* po = psum + BB * HH * NCHU; // 8*12*8*64
    float* xf = po + (size_t)BB * HH * NCHU * 64;  // 8*768

    hipMemsetAsync(ctrl, 0, 16384, stream);
    k_all<<<GRID_, 256, 0, stream>>>(
        ids, posp, past_k, past_v, wte, wpe, ln1g, ln1b, aw, ab, pw, pb,
        ln2g, ln2b, fw, fb, fpw, fpb, lnfg, lnfb,
        logits, okeys, ovals, ctrl,
        hB, hA, tmlp, tproj, qkv, fcbuf, pm, psum, po, xf);
}